// Round 8
// baseline (4592.887 us; speedup 1.0000x reference)
//
#include <hip/hip_runtime.h>
#include <cstdint>
#include <cstddef>

#define HDIM 2048
#define VOCAB 32000
#define BT 4096      // B*T tokens
#define NVB 125     // VOCAB / 256
#define BETA_F 0.1f
#define SCALE_X 16.0f
#define SCALE_W 64.0f
#define INV_SC (1.0f / (SCALE_X * SCALE_W))
#define ID_SCALE 0x7f7f7f7f  // E8M0 identity (2^0) x4

typedef float f32x16 __attribute__((ext_vector_type(16)));
typedef int i32x4v __attribute__((ext_vector_type(4)));
typedef int i32x8v __attribute__((ext_vector_type(8)));

// ---------------------------------------------------------------- helpers
__device__ __forceinline__ void async_lds16(const void* g, void* l) {
  __builtin_amdgcn_global_load_lds(
      (__attribute__((address_space(1))) void*)g,
      (__attribute__((address_space(3))) void*)l,
      16, 0, 0);
}

#define BAR() __builtin_amdgcn_s_barrier()
#define VMCNT(n) do { asm volatile("s_waitcnt vmcnt(" #n ")" ::: "memory"); \
                      __builtin_amdgcn_sched_barrier(0); } while (0)

// ---------------------------------------------------------------- cast fp32 -> fp8 e4m3 (16 elems/thread), scaled
__global__ void cast_fp8_kernel(const float* __restrict__ src,
                                uint4* __restrict__ dst, int n16, float scale) {
  int i = blockIdx.x * blockDim.x + threadIdx.x;
  int stride = gridDim.x * blockDim.x;
  for (; i < n16; i += stride) {
    const float4* s = (const float4*)src + (size_t)i * 4;
    uint4 o;
    {
      float4 a = s[0];
      int r = __builtin_amdgcn_cvt_pk_fp8_f32(a.x * scale, a.y * scale, 0, false);
      o.x = __builtin_amdgcn_cvt_pk_fp8_f32(a.z * scale, a.w * scale, r, true);
    }
    {
      float4 a = s[1];
      int r = __builtin_amdgcn_cvt_pk_fp8_f32(a.x * scale, a.y * scale, 0, false);
      o.y = __builtin_amdgcn_cvt_pk_fp8_f32(a.z * scale, a.w * scale, r, true);
    }
    {
      float4 a = s[2];
      int r = __builtin_amdgcn_cvt_pk_fp8_f32(a.x * scale, a.y * scale, 0, false);
      o.z = __builtin_amdgcn_cvt_pk_fp8_f32(a.z * scale, a.w * scale, r, true);
    }
    {
      float4 a = s[3];
      int r = __builtin_amdgcn_cvt_pk_fp8_f32(a.x * scale, a.y * scale, 0, false);
      o.w = __builtin_amdgcn_cvt_pk_fp8_f32(a.z * scale, a.w * scale, r, true);
    }
    dst[i] = o;
  }
}

// ---------------------------------------------------------------- 256x256 MX-fp8 GEMM + LSE partials
// 4 waves, 128x128 wave-tile (acc[4][4] f32x16 = 256 regs), 1 phase per K-tile:
//   {STAGE(t+1) -> READ 16 b128 -> 16 MFMA -> vmcnt(0) -> barrier}
// 32 barriers total (vs 128 in the 4-phase/8-wave version); stage latency is
// covered by the MFMA cluster; LDS-read:MFMA ratio 1.0 (was 1.5).
//
// LDS half-tile (8 KiB) storage map (R7-verified: 0 bank conflicts, absmax 0):
//   chunk (r, c) [c = 16B K-chunk 0..3] stored at
//   offset = (r>>5)*2048 + (c&1)*1024 + (r&15)*64 + (c>>1)*32 + ((r>>4)&1)*16
//            ^ ((r>>3 & 1) << 5)
// Read: lane l (h=l>>5) reads chunks {2h,2h+1} of its row as two ds_read_b128
// at phys p, p+1024 (conflict-free quarter-wave pattern). Staging granule
// g = 2*w + j (wave w, call j), source address = map inverse (re-derived from
// the same bit-fields; dest = w*2048 + j*1024 linear).
//
// NOTE __launch_bounds__(256,1): NO register cap. acc needs 256 regs/wave;
// any cap below ~340 spills acc to scratch (R4: 37 GB HBM traffic, 6x slower).
__global__ __launch_bounds__(256, 1) void gemm_lse256(
    const unsigned char* __restrict__ Xq,
    const unsigned char* __restrict__ Xrq,
    const unsigned char* __restrict__ Wq,
    const unsigned char* __restrict__ Wrq,
    float2* __restrict__ part) {
  __shared__ __align__(16) char lds[2][2][2][8192];

  const int tid = threadIdx.x;
  const int lane = tid & 63;
  const int w = tid >> 6;        // wave 0..3
  const int wm = w >> 1;         // 0..1 : M-half owner (rows wm*128..+128)
  const int wn = w & 1;          // 0..1 : N-half owner (cols wn*128..+128)
  const int which = blockIdx.y;  // 0 = policy, 1 = reference

  // XCD-aware bijective swizzle: 2000 blocks = 8 XCDs x 250, mb fastest within chunk.
  const int lin = blockIdx.x;
  const int nl = (lin & 7) * 250 + (lin >> 3);
  const int mb = nl & 15;        // 0..15
  const int nb = nl >> 4;        // 0..124

  const unsigned char* A = which ? Xrq : Xq;
  const unsigned char* B = which ? Wrq : Wq;
  float2* pp = part + (size_t)which * BT * NVB;

  // ---- staging addressing (inverse of storage map; wave w stages rows
  //      w*32..+32 of each 128-row half, granules w*2048 + j*1024) ----
  const int srow = w * 32 + (lane & 1) * 16 + ((lane >> 2) & 15);
  const int scg = ((lane >> 1) & 1) ^ ((lane >> 5) & 1);
  const int scol = scg * 32;     // + j*16 per call
  const unsigned char* Ag = A + (size_t)(mb * 256 + srow) * HDIM + scol;
  const unsigned char* Bg = B + (size_t)(nb * 256 + srow) * HDIM + scol;

#define STAGE(opsel, buf, h, T) do {                                          \
    const unsigned char* _g = (opsel) ? Bg : Ag;                              \
    char* _l = &lds[buf][opsel][h][0] + w * 2048;                             \
    async_lds16(_g + (size_t)(h) * 128 * HDIM + (T) * 64,      _l);           \
    async_lds16(_g + (size_t)(h) * 128 * HDIM + (T) * 64 + 16, _l + 1024);    \
  } while (0)

  // ---- fragment read: chunks {2h, 2h+1} = two swizzled ds_read_b128 (p, p+1024)
  const int l31 = lane & 31;
  const int khalf = (lane >> 5) * 32;   // (c>>1)*32 for c = 2h
#define FRAG32(dst, halfptr, row) do {                                        \
    int _r = (row);                                                           \
    int _p = ((((_r >> 5) << 11) + ((_r & 15) << 6) + khalf +                 \
               (((_r >> 4) & 1) << 4)) ^ (((_r >> 3) & 1) << 5));             \
    i32x4v _lo = *(const i32x4v*)((halfptr) + _p);                            \
    i32x4v _hi = *(const i32x4v*)((halfptr) + _p + 1024);                     \
    dst = (i32x8v){_lo[0], _lo[1], _lo[2], _lo[3],                            \
                   _hi[0], _hi[1], _hi[2], _hi[3]};                           \
  } while (0)

  const char* Ah[2] = { &lds[0][0][wm][0], &lds[1][0][wm][0] };
  const char* Bh[2] = { &lds[0][1][wn][0], &lds[1][1][wn][0] };

  f32x16 acc[4][4] = {};
  i32x8v aF[4], bF[4];

  // ---- prologue: stage tile 0 into buf0
  STAGE(0, 0, 0, 0); STAGE(0, 0, 1, 0); STAGE(1, 0, 0, 0); STAGE(1, 0, 1, 0);
  VMCNT(0);
  BAR();

  // ---- main loop: 32 K-tiles, one phase each ----
  for (int t = 0; t < 32; ++t) {
    const int b = t & 1, nbuf = b ^ 1;
    const int tn = (t + 1 > 31) ? 31 : t + 1;   // tail restage = same bytes, safe

    // stage next tile first (longest latency cover under the MFMA cluster);
    // WAR: buf[nbuf] was read at t-1, protected by t-1's end barrier.
    STAGE(0, nbuf, 0, tn); STAGE(0, nbuf, 1, tn);
    STAGE(1, nbuf, 0, tn); STAGE(1, nbuf, 1, tn);

    // read this tile's fragments (compiler inserts fine-grained lgkmcnt)
#pragma unroll
    for (int mi = 0; mi < 4; ++mi) FRAG32(aF[mi], Ah[b], mi * 32 + l31);
#pragma unroll
    for (int ni = 0; ni < 4; ++ni) FRAG32(bF[ni], Bh[b], ni * 32 + l31);

    __builtin_amdgcn_s_setprio(1);
#pragma unroll
    for (int mi = 0; mi < 4; ++mi)
#pragma unroll
      for (int ni = 0; ni < 4; ++ni)
        acc[mi][ni] = __builtin_amdgcn_mfma_scale_f32_32x32x64_f8f6f4(
            aF[mi], bF[ni], acc[mi][ni], 0, 0, 0, ID_SCALE, 0, ID_SCALE);
    __builtin_amdgcn_s_setprio(0);

    VMCNT(0);                    // next tile fully landed (before any wave reads it)
    BAR();
  }

  // ---- fused LSE epilogue over this block's 256 vocab cols ----
  // 32x32 C/D layout: col = lane&31, row = (reg&3) + 8*(reg>>2) + 4*(lane>>5).
  float* red = (float*)&lds[0][0][0][0];   // m: [wn*256+row], s: [512 + wn*256+row]
#pragma unroll
  for (int mi = 0; mi < 4; ++mi) {
#pragma unroll
    for (int r = 0; r < 16; ++r) {
      float v0 = acc[mi][0][r] * INV_SC;
      float v1 = acc[mi][1][r] * INV_SC;
      float v2 = acc[mi][2][r] * INV_SC;
      float v3 = acc[mi][3][r] * INV_SC;
      float m = fmaxf(fmaxf(v0, v1), fmaxf(v2, v3));
#pragma unroll
      for (int o = 1; o < 32; o <<= 1) m = fmaxf(m, __shfl_xor(m, o, 64));
      float s = __expf(v0 - m) + __expf(v1 - m) + __expf(v2 - m) + __expf(v3 - m);
#pragma unroll
      for (int o = 1; o < 32; o <<= 1) s += __shfl_xor(s, o, 64);
      if (l31 == 0) {
        int row = wm * 128 + mi * 32 + (r & 3) + 8 * (r >> 2) + 4 * (lane >> 5);
        red[wn * 256 + row] = m;
        red[512 + wn * 256 + row] = s;
      }
    }
  }
  __syncthreads();
  if (tid < 256) {
    float m0 = red[tid], m1 = red[256 + tid];
    float M = fmaxf(m0, m1);
    float S = red[512 + tid] * __expf(m0 - M) + red[768 + tid] * __expf(m1 - M);
    pp[(size_t)(mb * 256 + tid) * NVB + nb] = make_float2(M, S);
  }
#undef STAGE
#undef FRAG32
}

// ---------------------------------------------------------------- exact fp32 target logit: dot(x, W[y])
__global__ void target_logit(const float* __restrict__ x, const float* __restrict__ xr,
                             const float* __restrict__ W, const float* __restrict__ Wr,
                             const int* __restrict__ y, float* __restrict__ tlog) {
  int wid = (blockIdx.x * blockDim.x + threadIdx.x) >> 6;  // 0..8191
  int lane = threadIdx.x & 63;
  int which = wid >> 12;
  int tok = wid & 4095;
  int yy = y[tok];
  int ys = (yy == -100) ? 0 : yy;
  const float* xv = (which ? xr : x) + (size_t)tok * HDIM;
  const float* wv = (which ? Wr : W) + (size_t)ys * HDIM;
  const float4* x4 = (const float4*)xv;
  const float4* w4 = (const float4*)wv;
  float sum = 0.f;
  for (int i = lane; i < HDIM / 4; i += 64) {
    float4 a = x4[i], b = w4[i];
    sum += a.x * b.x + a.y * b.y + a.z * b.z + a.w * b.w;
  }
#pragma unroll
  for (int o = 1; o < 64; o <<= 1) sum += __shfl_xor(sum, o, 64);
  if (lane == 0) tlog[wid] = sum;
}

// ---------------------------------------------------------------- merge partials -> per-token logp
__global__ void lse_combine(const float2* __restrict__ part,
                            const float* __restrict__ tlog,
                            float* __restrict__ ptok) {
  int wid = (blockIdx.x * blockDim.x + threadIdx.x) >> 6;  // 0..8191
  int lane = threadIdx.x & 63;
  const float2* p = part + (size_t)wid * NVB;
  float m = -INFINITY, s = 0.f;
  for (int i = lane; i < NVB; i += 64) {
    float2 v = p[i];
    float M = fmaxf(m, v.x);
    s = s * __expf(m - M) + v.y * __expf(v.x - M);
    m = M;
  }
#pragma unroll
  for (int o = 1; o < 64; o <<= 1) {
    float mo = __shfl_xor(m, o, 64);
    float so = __shfl_xor(s, o, 64);
    float M = fmaxf(m, mo);
    s = s * __expf(m - M) + so * __expf(mo - M);
    m = M;
  }
  if (lane == 0) ptok[wid] = tlog[wid] - (m + logf(s));
}

// ---------------------------------------------------------------- masked per-seq mean + DPO loss
__global__ void final_loss(const float* __restrict__ ptok,
                           const int* __restrict__ y, float* __restrict__ out) {
  __shared__ float rs[256];
  __shared__ float rc[256];
  __shared__ float seq[8];
  int tid = threadIdx.x;
  for (int s = 0; s < 8; ++s) {
    int which = s >> 2, b = s & 3;
    float lsum = 0.f, lcnt = 0.f;
    for (int t = tid; t < 1024; t += 256) {
      int yy = y[b * 1024 + t];
      if (yy != -100) {
        lsum += ptok[which * 4096 + b * 1024 + t];
        lcnt += 1.f;
      }
    }
    rs[tid] = lsum; rc[tid] = lcnt;
    __syncthreads();
    for (int o = 128; o > 0; o >>= 1) {
      if (tid < o) { rs[tid] += rs[tid + o]; rc[tid] += rc[tid + o]; }
      __syncthreads();
    }
    if (tid == 0) seq[s] = rs[0] / rc[0];
    __syncthreads();
  }
  if (tid == 0) {
    float d0 = BETA_F * ((seq[0] - seq[4]) - (seq[2] - seq[6]));
    float d1 = BETA_F * ((seq[1] - seq[5]) - (seq[3] - seq[7]));
    auto sp = [](float a) { return fmaxf(a, 0.f) + log1pf(expf(-fabsf(a))); };
    out[0] = (sp(-d0) + sp(-d1)) * 0.5f;
  }
}

// ---------------------------------------------------------------- launch
extern "C" void kernel_launch(void* const* d_in, const int* in_sizes, int n_in,
                              void* d_out, int out_size, void* d_ws, size_t ws_size,
                              hipStream_t stream) {
  const float* x   = (const float*)d_in[0];
  const float* xr  = (const float*)d_in[1];
  const int*   y   = (const int*)d_in[2];
  const float* Wf  = (const float*)d_in[3];
  const float* Wrf = (const float*)d_in[4];
  float* out = (float*)d_out;

  char* ws = (char*)d_ws;
  size_t off = 0;
  auto alloc = [&](size_t bytes) -> void* {
    void* p = ws + off;
    off = (off + bytes + 255) & ~(size_t)255;
    return p;
  };
  unsigned char* Xq  = (unsigned char*)alloc((size_t)BT * HDIM);
  unsigned char* Xrq = (unsigned char*)alloc((size_t)BT * HDIM);
  unsigned char* Wq  = (unsigned char*)alloc((size_t)VOCAB * HDIM);
  unsigned char* Wrq = (unsigned char*)alloc((size_t)VOCAB * HDIM);
  float2* part = (float2*)alloc((size_t)2 * BT * NVB * sizeof(float2));
  float*  tlog = (float*)alloc((size_t)2 * BT * sizeof(float));
  float*  ptok = (float*)alloc((size_t)2 * BT * sizeof(float));

  cast_fp8_kernel<<<2048, 256, 0, stream>>>(x,  (uint4*)Xq,  BT * HDIM / 16, SCALE_X);
  cast_fp8_kernel<<<2048, 256, 0, stream>>>(xr, (uint4*)Xrq, BT * HDIM / 16, SCALE_X);
  cast_fp8_kernel<<<2048, 256, 0, stream>>>(Wf,  (uint4*)Wq,  VOCAB * HDIM / 16, SCALE_W);
  cast_fp8_kernel<<<2048, 256, 0, stream>>>(Wrf, (uint4*)Wrq, VOCAB * HDIM / 16, SCALE_W);

  dim3 gg(2000, 2);
  gemm_lse256<<<gg, 256, 0, stream>>>(Xq, Xrq, Wq, Wrq, part);

  target_logit<<<2048, 256, 0, stream>>>(x, xr, Wf, Wrf, y, tlog);
  lse_combine<<<2048, 256, 0, stream>>>(part, tlog, ptok);
  final_loss<<<1, 256, 0, stream>>>(ptok, y, out);
}

// Round 9
// 961.338 us; speedup vs baseline: 4.7776x; 4.7776x over previous
//
#include <hip/hip_runtime.h>
#include <cstdint>
#include <cstddef>

#define HDIM 2048
#define VOCAB 32000
#define BT 4096      // B*T tokens
#define NVB 125      // VOCAB / 256
#define BETA_F 0.1f
#define SCALE_X 16.0f
#define SCALE_W 64.0f
#define INV_SC (1.0f / (SCALE_X * SCALE_W))

typedef float f32x4 __attribute__((ext_vector_type(4)));
typedef long lx2 __attribute__((ext_vector_type(2)));

// ---------------------------------------------------------------- helpers
__device__ __forceinline__ void async_lds16(const void* g, void* l) {
  __builtin_amdgcn_global_load_lds(
      (__attribute__((address_space(1))) void*)g,
      (__attribute__((address_space(3))) void*)l,
      16, 0, 0);
}

#define BAR() __builtin_amdgcn_s_barrier()
#define SCHED0() __builtin_amdgcn_sched_barrier(0)
#define VMCNT(n) do { asm volatile("s_waitcnt vmcnt(" #n ")" ::: "memory"); \
                      __builtin_amdgcn_sched_barrier(0); } while (0)

// ---------------------------------------------------------------- cast fp32 -> fp8 e4m3 (16 elems/thread), scaled
__global__ void cast_fp8_kernel(const float* __restrict__ src,
                                uint4* __restrict__ dst, int n16, float scale) {
  int i = blockIdx.x * blockDim.x + threadIdx.x;
  int stride = gridDim.x * blockDim.x;
  for (; i < n16; i += stride) {
    const float4* s = (const float4*)src + (size_t)i * 4;
    uint4 o;
    {
      float4 a = s[0];
      int r = __builtin_amdgcn_cvt_pk_fp8_f32(a.x * scale, a.y * scale, 0, false);
      o.x = __builtin_amdgcn_cvt_pk_fp8_f32(a.z * scale, a.w * scale, r, true);
    }
    {
      float4 a = s[1];
      int r = __builtin_amdgcn_cvt_pk_fp8_f32(a.x * scale, a.y * scale, 0, false);
      o.y = __builtin_amdgcn_cvt_pk_fp8_f32(a.z * scale, a.w * scale, r, true);
    }
    {
      float4 a = s[2];
      int r = __builtin_amdgcn_cvt_pk_fp8_f32(a.x * scale, a.y * scale, 0, false);
      o.z = __builtin_amdgcn_cvt_pk_fp8_f32(a.z * scale, a.w * scale, r, true);
    }
    {
      float4 a = s[3];
      int r = __builtin_amdgcn_cvt_pk_fp8_f32(a.x * scale, a.y * scale, 0, false);
      o.w = __builtin_amdgcn_cvt_pk_fp8_f32(a.z * scale, a.w * scale, r, true);
    }
    dst[i] = o;
  }
}

// ---------------------------------------------------------------- 256x256 fp8 GEMM + LSE partials
// R5's verified tile/LDS/staging/epilogue with a re-pipelined K-loop:
//   - quadrant fragment prefetch (reads issued one phase before use; compiler
//     emits counted lgkmcnt -> reads drain under MFMAs)
//   - 2 barriers per iteration (buffer handoffs only), vmcnt(0) there waits on
//     exactly the 4 stage-ops of the tile about to be read (4-phase cover)
//   - all 4 stage ops of a tile issued together right after the barrier that
//     retires that buffer's reads (WAR-safe by barrier ordering)
//
// LDS half-tile: [row(128)][4 chunks x 16B], chunk c of a row's 64-B K-slab =
// [kk0-slot-c | kk1-slot-c] (K-permutation, cancels between A and B). One
// ds_read_b128 per row yields both kk fragments, conflict-free (R5: 0 conflicts).
// Swizzle: physical ^= ((row>>3)&1)<<5; staging source pre-swizzled.
//
// NOTE launch_bounds(512,2): 1 block/CU by design. acc[8][4] f32x4 = 128 regs;
// capping VGPRs below ~232 spills acc (R4/R8: 5-37 GB scratch traffic, 5-6x
// slower). Do not raise requested occupancy.
__global__ __launch_bounds__(512, 2) void gemm_lse256(
    const unsigned char* __restrict__ Xq,
    const unsigned char* __restrict__ Xrq,
    const unsigned char* __restrict__ Wq,
    const unsigned char* __restrict__ Wrq,
    float2* __restrict__ part) {
  __shared__ __align__(16) char lds[2][2][2][8192];

  const int tid = threadIdx.x;
  const int lane = tid & 63;
  const int w = tid >> 6;        // wave 0..7
  const int wm = w >> 2;         // 0..1 : M-half owner
  const int wn = w & 3;          // 0..3 : N-quarter owner
  const int which = blockIdx.y;  // 0 = policy, 1 = reference

  // XCD-aware bijective swizzle: 2000 blocks = 8 XCDs x 250, mb fastest within chunk.
  const int lin = blockIdx.x;
  const int nl = (lin & 7) * 250 + (lin >> 3);
  const int mb = nl & 15;        // 0..15
  const int nb = nl >> 4;        // 0..124

  const unsigned char* A = which ? Xrq : Xq;
  const unsigned char* B = which ? Wrq : Wq;
  float2* pp = part + (size_t)which * BT * NVB;

  // ---- staging addressing (source pre-swizzled to undo read-side XOR) ----
  const int lanep = lane ^ ((lane & 32) >> 4);
  const int rw = w * 16 + (lanep >> 2);     // row within 128-row half
  const int cw = (lanep & 3) * 16;          // byte col within 64-B K-slab
  const unsigned char* Ag = A + (size_t)(mb * 256 + rw) * HDIM + cw;
  const unsigned char* Bg = B + (size_t)(nb * 256 + rw) * HDIM + cw;

#define STAGE(opsel, buf, h, T) do {                                          \
    const unsigned char* _g = (opsel) ? Bg : Ag;                              \
    async_lds16(_g + (size_t)(h) * 128 * HDIM + (T) * 64,                     \
                &lds[buf][opsel][h][0] + w * 1024);                           \
  } while (0)
#define STAGE4(buf, T) do {                                                   \
    STAGE(0, buf, 0, T); STAGE(0, buf, 1, T);                                 \
    STAGE(1, buf, 0, T); STAGE(1, buf, 1, T);                                 \
  } while (0)

  // ---- paired fragment read (swizzled b128 -> kk0 + kk1), R5-verified ----
  const int l15 = lane & 15;
  const int kbyte = (lane >> 4) * 16;
#define FRAGP(d0, d1, halfptr, row) do {                                      \
    int _r = (row);                                                           \
    int _L = _r * 64 + kbyte;                                                 \
    lx2 _v = *(const lx2*)((halfptr) + (_L ^ (((_r >> 3) & 1) << 5)));        \
    d0 = _v.x; d1 = _v.y;                                                     \
  } while (0)

  const char* Ah[2] = { &lds[0][0][wm][0], &lds[1][0][wm][0] };
  const char* Bh[2] = { &lds[0][1][wn >> 1][0], &lds[1][1][wn >> 1][0] };
  const int brow = (wn & 1) * 64;

  f32x4 acc[8][4] = {};
  long aLo[4][2], aHi[4][2], bLo[2][2], bHi[2][2];

#define RD_ALO(buf) do {                                                      \
    _Pragma("unroll") for (int mi = 0; mi < 4; ++mi)                          \
      FRAGP(aLo[mi][0], aLo[mi][1], Ah[buf], mi * 16 + l15);                  \
  } while (0)
#define RD_AHI(buf) do {                                                      \
    _Pragma("unroll") for (int mi = 0; mi < 4; ++mi)                          \
      FRAGP(aHi[mi][0], aHi[mi][1], Ah[buf], (4 + mi) * 16 + l15);            \
  } while (0)
#define RD_B01(buf) do {                                                      \
    _Pragma("unroll") for (int ni = 0; ni < 2; ++ni)                          \
      FRAGP(bLo[ni][0], bLo[ni][1], Bh[buf], brow + ni * 16 + l15);           \
  } while (0)
#define RD_B23(buf) do {                                                      \
    _Pragma("unroll") for (int ni = 0; ni < 2; ++ni)                          \
      FRAGP(bHi[ni][0], bHi[ni][1], Bh[buf], brow + (2 + ni) * 16 + l15);     \
  } while (0)
  // quadrant MFMA: 16 x mfma_f32_16x16x32_fp8_fp8
#define MFMA_Q(AG, BG, MI0, NI0) do {                                         \
    __builtin_amdgcn_s_setprio(1);                                            \
    _Pragma("unroll") for (int kk = 0; kk < 2; ++kk)                          \
    _Pragma("unroll") for (int mi = 0; mi < 4; ++mi)                          \
    _Pragma("unroll") for (int ni = 0; ni < 2; ++ni)                          \
      acc[(MI0) + mi][(NI0) + ni] = __builtin_amdgcn_mfma_f32_16x16x32_fp8_fp8( \
          AG[mi][kk], BG[ni][kk], acc[(MI0) + mi][(NI0) + ni], 0, 0, 0);      \
    __builtin_amdgcn_s_setprio(0);                                            \
  } while (0)

  // ---- prologue: stage tiles 0 (buf0) and 1 (buf1); prefetch Q1(t0) ----
  STAGE4(0, 0);
  STAGE4(1, 1);
  VMCNT(4);                      // tile0's 4 ops landed (tile1's 4 in flight)
  BAR(); SCHED0();
  RD_ALO(0); RD_B01(0);
  SCHED0();

  // ---- main loop: 16 iterations, 2 K-tiles each ----
  for (int i = 0; i < 16; ++i) {
    const int se = (2 * i + 2 > 30) ? 30 : 2 * i + 2;  // even tile -> buf0
    const int so = (2 * i + 3 > 31) ? 31 : 2 * i + 3;  // odd  tile -> buf1

    // P1: MFMA Q1(t0) [aLo x bLo]; issue bHi(t0)
    RD_B23(0); SCHED0();
    MFMA_Q(aLo, bLo, 0, 0); SCHED0();
    // P2: MFMA Q2(t0) [aLo x bHi]; issue aHi(t0)
    RD_AHI(0); SCHED0();
    MFMA_Q(aLo, bHi, 0, 2); SCHED0();
    // P3: MFMA Q3(t0) [aHi x bLo]
    MFMA_Q(aHi, bLo, 4, 0); SCHED0();
    // P4: handoff -> buf1. t1's stages (issued prev P8) landed; buf0 reads
    // all retired (compiler waits before P2/P3 MFMAs) in every wave => stage
    // se into buf0 is WAR-safe after BAR.
    VMCNT(0);
    BAR(); SCHED0();
    STAGE4(0, se);
    RD_ALO(1); RD_B01(1); SCHED0();
    MFMA_Q(aHi, bHi, 4, 2); SCHED0();          // operands already in regs

    // P5: MFMA Q1(t1); issue bHi(t1)
    RD_B23(1); SCHED0();
    MFMA_Q(aLo, bLo, 0, 0); SCHED0();
    // P6: MFMA Q2(t1); issue aHi(t1)
    RD_AHI(1); SCHED0();
    MFMA_Q(aLo, bHi, 0, 2); SCHED0();
    // P7: MFMA Q3(t1)
    MFMA_Q(aHi, bLo, 4, 0); SCHED0();
    // P8: handoff -> buf0. se's stages landed; buf1 reads retired => stage so.
    VMCNT(0);
    BAR(); SCHED0();
    STAGE4(1, so);
    RD_ALO(0); RD_B01(0); SCHED0();
    MFMA_Q(aHi, bHi, 4, 2); SCHED0();
  }
  VMCNT(0);                      // drain tail re-stages before LDS reuse
  BAR(); SCHED0();

  // ---- fused LSE epilogue over this block's 256 vocab cols (R5-verified) ----
  // C/D layout: col = lane&15, row = (lane>>4)*4 + reg. Un-scale by INV_SC.
  float* red = (float*)&lds[0][0][0][0];
#pragma unroll
  for (int mi = 0; mi < 8; ++mi) {
#pragma unroll
    for (int r = 0; r < 4; ++r) {
      float v0 = acc[mi][0][r] * INV_SC;
      float v1 = acc[mi][1][r] * INV_SC;
      float v2 = acc[mi][2][r] * INV_SC;
      float v3 = acc[mi][3][r] * INV_SC;
      float m = fmaxf(fmaxf(v0, v1), fmaxf(v2, v3));
#pragma unroll
      for (int o = 1; o < 16; o <<= 1) m = fmaxf(m, __shfl_xor(m, o, 64));
      float s = __expf(v0 - m) + __expf(v1 - m) + __expf(v2 - m) + __expf(v3 - m);
#pragma unroll
      for (int o = 1; o < 16; o <<= 1) s += __shfl_xor(s, o, 64);
      if (l15 == 0) {
        int row = wm * 128 + mi * 16 + (lane >> 4) * 4 + r;
        red[wn * 256 + row] = m;
        red[1024 + wn * 256 + row] = s;
      }
    }
  }
  __syncthreads();
  if (tid < 256) {
    float m0 = red[tid], m1 = red[256 + tid], m2 = red[512 + tid], m3 = red[768 + tid];
    float M = fmaxf(fmaxf(m0, m1), fmaxf(m2, m3));
    float S = red[1024 + tid] * __expf(m0 - M) + red[1280 + tid] * __expf(m1 - M) +
              red[1536 + tid] * __expf(m2 - M) + red[1792 + tid] * __expf(m3 - M);
    pp[(size_t)(mb * 256 + tid) * NVB + nb] = make_float2(M, S);
  }
#undef STAGE
#undef STAGE4
#undef FRAGP
#undef RD_ALO
#undef RD_AHI
#undef RD_B01
#undef RD_B23
#undef MFMA_Q
}

// ---------------------------------------------------------------- exact fp32 target logit: dot(x, W[y])
__global__ void target_logit(const float* __restrict__ x, const float* __restrict__ xr,
                             const float* __restrict__ W, const float* __restrict__ Wr,
                             const int* __restrict__ y, float* __restrict__ tlog) {
  int wid = (blockIdx.x * blockDim.x + threadIdx.x) >> 6;  // 0..8191
  int lane = threadIdx.x & 63;
  int which = wid >> 12;
  int tok = wid & 4095;
  int yy = y[tok];
  int ys = (yy == -100) ? 0 : yy;
  const float* xv = (which ? xr : x) + (size_t)tok * HDIM;
  const float* wv = (which ? Wr : W) + (size_t)ys * HDIM;
  const float4* x4 = (const float4*)xv;
  const float4* w4 = (const float4*)wv;
  float sum = 0.f;
  for (int i = lane; i < HDIM / 4; i += 64) {
    float4 a = x4[i], b = w4[i];
    sum += a.x * b.x + a.y * b.y + a.z * b.z + a.w * b.w;
  }
#pragma unroll
  for (int o = 1; o < 64; o <<= 1) sum += __shfl_xor(sum, o, 64);
  if (lane == 0) tlog[wid] = sum;
}

// ---------------------------------------------------------------- merge partials -> per-token logp
__global__ void lse_combine(const float2* __restrict__ part,
                            const float* __restrict__ tlog,
                            float* __restrict__ ptok) {
  int wid = (blockIdx.x * blockDim.x + threadIdx.x) >> 6;  // 0..8191
  int lane = threadIdx.x & 63;
  const float2* p = part + (size_t)wid * NVB;
  float m = -INFINITY, s = 0.f;
  for (int i = lane; i < NVB; i += 64) {
    float2 v = p[i];
    float M = fmaxf(m, v.x);
    s = s * __expf(m - M) + v.y * __expf(v.x - M);
    m = M;
  }
#pragma unroll
  for (int o = 1; o < 64; o <<= 1) {
    float mo = __shfl_xor(m, o, 64);
    float so = __shfl_xor(s, o, 64);
    float M = fmaxf(m, mo);
    s = s * __expf(m - M) + so * __expf(mo - M);
    m = M;
  }
  if (lane == 0) ptok[wid] = tlog[wid] - (m + logf(s));
}

// ---------------------------------------------------------------- masked per-seq mean + DPO loss
__global__ void final_loss(const float* __restrict__ ptok,
                           const int* __restrict__ y, float* __restrict__ out) {
  __shared__ float rs[256];
  __shared__ float rc[256];
  __shared__ float seq[8];
  int tid = threadIdx.x;
  for (int s = 0; s < 8; ++s) {
    int which = s >> 2, b = s & 3;
    float lsum = 0.f, lcnt = 0.f;
    for (int t = tid; t < 1024; t += 256) {
      int yy = y[b * 1024 + t];
      if (yy != -100) {
        lsum += ptok[which * 4096 + b * 1024 + t];
        lcnt += 1.f;
      }
    }
    rs[tid] = lsum; rc[tid] = lcnt;
    __syncthreads();
    for (int o = 128; o > 0; o >>= 1) {
      if (tid < o) { rs[tid] += rs[tid + o]; rc[tid] += rc[tid + o]; }
      __syncthreads();
    }
    if (tid == 0) seq[s] = rs[0] / rc[0];
    __syncthreads();
  }
  if (tid == 0) {
    float d0 = BETA_F * ((seq[0] - seq[4]) - (seq[2] - seq[6]));
    float d1 = BETA_F * ((seq[1] - seq[5]) - (seq[3] - seq[7]));
    auto sp = [](float a) { return fmaxf(a, 0.f) + log1pf(expf(-fabsf(a))); };
    out[0] = (sp(-d0) + sp(-d1)) * 0.5f;
  }
}

// ---------------------------------------------------------------- launch
extern "C" void kernel_launch(void* const* d_in, const int* in_sizes, int n_in,
                              void* d_out, int out_size, void* d_ws, size_t ws_size,
                              hipStream_t stream) {
  const float* x   = (const float*)d_in[0];
  const float* xr  = (const float*)d_in[1];
  const int*   y   = (const int*)d_in[2];
  const float* Wf  = (const float*)d_in[3];
  const float* Wrf = (const float*)d_in[4];
  float* out = (float*)d_out;

  char* ws = (char*)d_ws;
  size_t off = 0;
  auto alloc = [&](size_t bytes) -> void* {
    void* p = ws + off;
    off = (off + bytes + 255) & ~(size_t)255;
    return p;
  };
  unsigned char* Xq  = (unsigned char*)alloc((size_t)BT * HDIM);
  unsigned char* Xrq = (unsigned char*)alloc((size_t)BT * HDIM);
  unsigned char* Wq  = (unsigned char*)alloc((size_t)VOCAB * HDIM);
  unsigned char* Wrq = (unsigned char*)alloc((size_t)VOCAB * HDIM);
  float2* part = (float2*)alloc((size_t)2 * BT * NVB * sizeof(float2));
  float*  tlog = (float*)alloc((size_t)2 * BT * sizeof(float));
  float*  ptok = (float*)alloc((size_t)2 * BT * sizeof(float));

  cast_fp8_kernel<<<2048, 256, 0, stream>>>(x,  (uint4*)Xq,  BT * HDIM / 16, SCALE_X);
  cast_fp8_kernel<<<2048, 256, 0, stream>>>(xr, (uint4*)Xrq, BT * HDIM / 16, SCALE_X);
  cast_fp8_kernel<<<2048, 256, 0, stream>>>(Wf,  (uint4*)Wq,  VOCAB * HDIM / 16, SCALE_W);
  cast_fp8_kernel<<<2048, 256, 0, stream>>>(Wrf, (uint4*)Wrq, VOCAB * HDIM / 16, SCALE_W);

  dim3 gg(2000, 2);
  gemm_lse256<<<gg, 512, 0, stream>>>(Xq, Xrq, Wq, Wrq, part);

  target_logit<<<2048, 256, 0, stream>>>(x, xr, Wf, Wrf, y, tlog);
  lse_combine<<<2048, 256, 0, stream>>>(part, tlog, ptok);
  final_loss<<<1, 256, 0, stream>>>(ptok, y, out);
}